// Round 1
// baseline (86.058 us; speedup 1.0000x reference)
//
#include <hip/hip_runtime.h>

// FHE BSGS: out[b,s] = sum_{t=0..15} x[b,(s+2^t)&0xFFFF] * diag[t,s], rolled by 32768.
// Roll by S/2 on the 2^16 ring == store to column s ^ 0x8000 (coalesced).
//
// v7: same request bytes / shuffle structure as v6, restructured for occupancy.
// v6 held all 16 diag float4 in registers (64 VGPR) + per-row vd[7]+w[6] -> ~160 VGPR
// -> 2 waves/SIMD. Latency/MLP-bound regime (2.8 TB/s request rate, far below both
// HBM and L2 ceilings; rate calibrated ~proportional to resident blocks), so VGPRs
// are the real throughput knob.
// Two-phase t-outer form, peak live set ~100 VGPR, enforced by __launch_bounds__(256,4):
//   phase 1 (t=0..8): vA/vE only; windows at shifts 4..128 via wave shuffles (DS pipe),
//                     diag streamed one t at a time.
//   phase 2 (t=9..15): vA/vE/w1 dead; direct loads, compiler pipelines ~2 t-steps
//                      of (diag + 4 row loads) under the 128-VGPR cap.

#define SLOTS 65536
#define MASK  65535
#define NB    4

__device__ __forceinline__ float4 shfl4(const float4 v, int lsel) {
    return make_float4(__shfl(v.x, lsel, 64), __shfl(v.y, lsel, 64),
                       __shfl(v.z, lsel, 64), __shfl(v.w, lsel, 64));
}

// Window at shift 4k (k lanes ahead): take lane lane+k from vA, spilling into vE
// when the source lane falls past the wave boundary (vE = vA shifted by 256 cols).
__device__ __forceinline__ float4 window(const float4 vA, const float4 vE,
                                         int lane, int k) {
    const int lp = lane + k;
    const int ls = lp & 63;
    const float4 a = shfl4(vA, ls);
    const float4 e = shfl4(vE, ls);
    const bool useA = lp < 64;
    return make_float4(useA ? a.x : e.x, useA ? a.y : e.y,
                       useA ? a.z : e.z, useA ? a.w : e.w);
}

__global__ __launch_bounds__(256, 4) void bsgs_kernel(
    const float* __restrict__ x,
    const float* __restrict__ diag,
    float* __restrict__ out)
{
    const int bid  = blockIdx.x;          // 0..1023
    const int y    = bid & 15;            // batch group (XCD-friendly: bid%8 clusters)
    const int xidx = bid >> 4;            // column tile 0..63
    const int j    = xidx * 1024 + threadIdx.x * 4;   // column base (multiple of 4)
    const int bg   = y * NB;
    const int lane = threadIdx.x & 63;

    float4 acc[NB];
#pragma unroll
    for (int b = 0; b < NB; ++b) acc[b] = make_float4(0.f, 0.f, 0.f, 0.f);

    // ---------- phase 1: shifts 1..256 (t=0..8) -- only vA/vE x-loads ----------
    {
        float4 vA[NB], vE[NB];
#pragma unroll
        for (int b = 0; b < NB; ++b) {
            const float* __restrict__ xr = x + (size_t)(bg + b) * SLOTS;
            vA[b] = *(const float4*)(xr + j);
            vE[b] = *(const float4*)(xr + ((j + 256) & MASK));
        }

        // shift-4 window, reused by t=0,1,2
        float4 w1[NB];
#pragma unroll
        for (int b = 0; b < NB; ++b) w1[b] = window(vA[b], vE[b], lane, 1);

        // t=0 (shift 1): (vA.y, vA.z, vA.w, w1.x); t=1 (shift 2): (vA.z, vA.w, w1.x, w1.y)
        {
            const float4 d0 = *(const float4*)(diag + 0 * SLOTS + j);
            const float4 d1 = *(const float4*)(diag + 1 * SLOTS + j);
#pragma unroll
            for (int b = 0; b < NB; ++b) {
                acc[b].x += vA[b].y * d0.x + vA[b].z  * d1.x;
                acc[b].y += vA[b].z * d0.y + vA[b].w  * d1.y;
                acc[b].z += vA[b].w * d0.z + w1[b].x  * d1.z;
                acc[b].w += w1[b].x * d0.w + w1[b].y  * d1.w;
            }
        }
        // t=2 (shift 4): w1 itself
        {
            const float4 d = *(const float4*)(diag + 2 * SLOTS + j);
#pragma unroll
            for (int b = 0; b < NB; ++b) {
                acc[b].x += w1[b].x * d.x; acc[b].y += w1[b].y * d.y;
                acc[b].z += w1[b].z * d.z; acc[b].w += w1[b].w * d.w;
            }
        }
        // t=3..7 (shifts 8..128): on-the-fly shuffle windows, k = shift/4
#pragma unroll
        for (int t = 3; t <= 7; ++t) {
            const float4 d = *(const float4*)(diag + t * SLOTS + j);
            const int k = 1 << (t - 2);
#pragma unroll
            for (int b = 0; b < NB; ++b) {
                const float4 v = window(vA[b], vE[b], lane, k);
                acc[b].x += v.x * d.x; acc[b].y += v.y * d.y;
                acc[b].z += v.z * d.z; acc[b].w += v.w * d.w;
            }
        }
        // t=8 (shift 256): vE directly
        {
            const float4 d = *(const float4*)(diag + 8 * SLOTS + j);
#pragma unroll
            for (int b = 0; b < NB; ++b) {
                acc[b].x += vE[b].x * d.x; acc[b].y += vE[b].y * d.y;
                acc[b].z += vE[b].z * d.z; acc[b].w += vE[b].w * d.w;
            }
        }
    } // vA/vE/w1 die here -> ~48 VGPRs freed for phase-2 pipelining

    // ---------- phase 2: big shifts t=9..15 -- direct loads ----------
#pragma unroll
    for (int t = 9; t < 16; ++t) {
        const float4 d = *(const float4*)(diag + t * SLOTS + j);
        const int off = (j + (1 << t)) & MASK;
#pragma unroll
        for (int b = 0; b < NB; ++b) {
            const float4 v = *(const float4*)(x + (size_t)(bg + b) * SLOTS + off);
            acc[b].x += v.x * d.x; acc[b].y += v.y * d.y;
            acc[b].z += v.z * d.z; acc[b].w += v.w * d.w;
        }
    }

    // roll by 32768 == XOR top column bit; stores stay coalesced
#pragma unroll
    for (int b = 0; b < NB; ++b)
        *(float4*)(out + (size_t)(bg + b) * SLOTS + (j ^ 32768)) = acc[b];
}

extern "C" void kernel_launch(void* const* d_in, const int* in_sizes, int n_in,
                              void* d_out, int out_size, void* d_ws, size_t ws_size,
                              hipStream_t stream) {
    const float* x    = (const float*)d_in[0];   // (64, 65536) fp32
    const float* diag = (const float*)d_in[1];   // (16, 65536) fp32
    float* out        = (float*)d_out;           // (64, 65536) fp32
    // d_in[2] = stride (1), d_in[3] = reps (1) -- compile-time constants here.

    bsgs_kernel<<<dim3(1024), dim3(256), 0, stream>>>(x, diag, out);
}